// Round 7
// baseline (418.036 us; speedup 1.0000x reference)
//
#include <hip/hip_runtime.h>
#include <hip/hip_bf16.h>
#include <stdint.h>

typedef __attribute__((ext_vector_type(8))) short short8;
typedef __attribute__((ext_vector_type(4))) float floatx4;
typedef __fp16 h2 __attribute__((ext_vector_type(2)));

#define FEAT_DIM 1536
#define QD 64
#define NROWS 8192
#define TT 513

__device__ __forceinline__ unsigned short f2bf(float x) {
  union { float f; unsigned u; } t; t.f = x;
  unsigned r = t.u + 0x7fffu + ((t.u >> 16) & 1u);
  return (unsigned short)(r >> 16);
}
__device__ __forceinline__ float bf2f(unsigned short u) {
  union { float f; unsigned u; } t; t.u = ((unsigned)u) << 16;
  return t.f;
}

// K1: sf = win @ proj (MFMA bf16), proj transposed+converted on the fly.
// Also zero-inits cnt[256] + psum (runs before k_knn in stream order).
__global__ __launch_bounds__(256, 4) void k_sf(const float* __restrict__ feat,
                                               const float* __restrict__ proj,
                                               unsigned short* __restrict__ sfb,
                                               float* __restrict__ sq,
                                               unsigned* __restrict__ cnt,
                                               float* __restrict__ psum) {
  if (threadIdx.x == 0) {
    if (blockIdx.x < 256) cnt[blockIdx.x] = 0u;
    if (blockIdx.x == 256) *psum = 0.0f;
  }
  const int tid = threadIdx.x;
  const int wave = tid >> 6, lane = tid & 63;
  const int q = lane >> 4, n = lane & 15;
  const int rbase = blockIdx.x * 16;
  const int row = rbase + n;
  const int b = row >> 9, ti = row & 511;
  const float* fb = feat + (size_t)(b * TT + ti) * FEAT_DIM;
  const int kw = wave * 384;

  floatx4 acc0 = {0,0,0,0}, acc1 = {0,0,0,0}, acc2 = {0,0,0,0}, acc3 = {0,0,0,0};

  int koff = kw + q * 8;
  floatx4 f0 = *(const floatx4*)(fb + koff);
  floatx4 f1 = *(const floatx4*)(fb + koff + 4);
  floatx4 g0 = *(const floatx4*)(fb + FEAT_DIM + koff);
  floatx4 g1 = *(const floatx4*)(fb + FEAT_DIM + koff + 4);

  for (int ks = 0; ks < 12; ++ks) {
    floatx4 nf0, nf1, ng0, ng1;
    if (ks < 11) {
      int ko = kw + (ks + 1) * 32 + q * 8;
      nf0 = *(const floatx4*)(fb + ko);
      nf1 = *(const floatx4*)(fb + ko + 4);
      ng0 = *(const floatx4*)(fb + FEAT_DIM + ko);
      ng1 = *(const floatx4*)(fb + FEAT_DIM + ko + 4);
    }
    const float* pp = proj + (size_t)(kw + ks * 32 + q * 8) * QD + n;
    union { unsigned short u[8]; short8 v; } B0, B1, B2, B3;
#pragma unroll
    for (int j = 0; j < 8; ++j) {
      B0.u[j] = f2bf(pp[j * QD]);
      B1.u[j] = f2bf(pp[j * QD + 16]);
      B2.u[j] = f2bf(pp[j * QD + 32]);
      B3.u[j] = f2bf(pp[j * QD + 48]);
    }
    __builtin_amdgcn_sched_barrier(0);
    union { unsigned short u[8]; short8 v; } A;
#pragma unroll
    for (int j = 0; j < 4; ++j) A.u[j] = f2bf(0.5f * (f0[j] + g0[j]));
#pragma unroll
    for (int j = 0; j < 4; ++j) A.u[4 + j] = f2bf(0.5f * (f1[j] + g1[j]));
    acc0 = __builtin_amdgcn_mfma_f32_16x16x32_bf16(A.v, B0.v, acc0, 0, 0, 0);
    acc1 = __builtin_amdgcn_mfma_f32_16x16x32_bf16(A.v, B1.v, acc1, 0, 0, 0);
    acc2 = __builtin_amdgcn_mfma_f32_16x16x32_bf16(A.v, B2.v, acc2, 0, 0, 0);
    acc3 = __builtin_amdgcn_mfma_f32_16x16x32_bf16(A.v, B3.v, acc3, 0, 0, 0);
    if (ks < 11) { f0 = nf0; f1 = nf1; g0 = ng0; g1 = ng1; }
  }

  __shared__ float part[4][16][64];
#pragma unroll
  for (int r = 0; r < 4; ++r) {
    part[wave][q * 4 + r][0 * 16 + n] = acc0[r];
    part[wave][q * 4 + r][1 * 16 + n] = acc1[r];
    part[wave][q * 4 + r][2 * 16 + n] = acc2[r];
    part[wave][q * 4 + r][3 * 16 + n] = acc3[r];
  }
  __syncthreads();
  {
    const int r = tid >> 4;
    const int c0 = (tid & 15) * 4;
    float sqp = 0.0f;
    union { unsigned short u[4]; uint2 d; } P;
#pragma unroll
    for (int j = 0; j < 4; ++j) {
      float v = part[0][r][c0 + j] + part[1][r][c0 + j] +
                part[2][r][c0 + j] + part[3][r][c0 + j];
      P.u[j] = f2bf(v);
      float bv = bf2f(P.u[j]);
      sqp += bv * bv;
    }
    *(uint2*)(sfb + (size_t)(rbase + r) * QD + c0) = P.d;
#pragma unroll
    for (int off = 1; off < 16; off <<= 1) sqp += __shfl_xor(sqp, off, 64);
    if ((tid & 15) == 0) sq[rbase + r] = sqp;
  }
}

// K2: pairwise-dot (MFMA) + per-row top-16 with PACKED fp16 dual lists
// (one v_pk_min/max chain serves rows ib+n and ib+16+n; lists = 16 VGPRs).
// Block = (32-row i-tile) x (js of 1024 j's); wave covers 256 j's.
// Last-of-8 js-block per row-group merges (atomic cnt) -> intrew + psum.
__global__ __launch_bounds__(256, 5) void k_knn(const unsigned short* __restrict__ sfb,
                                                const float* __restrict__ sq,
                                                float* __restrict__ tops,
                                                float* __restrict__ intrew,
                                                unsigned* __restrict__ cnt,
                                                float* __restrict__ psum) {
  const int tid = threadIdx.x;
  const int wave = tid >> 6, lane = tid & 63;
  const int q = lane >> 4, n = lane & 15;
  const int rg = blockIdx.x >> 3;          // row-group 0..255
  const int ib = rg * 32;
  const int js = blockIdx.x & 7;
  const short8* sfv = (const short8*)sfb;

  short8 b0 = sfv[(ib + n) * 8 + q];
  short8 b1 = sfv[(ib + n) * 8 + 4 + q];
  short8 b2 = sfv[(ib + 16 + n) * 8 + q];
  short8 b3 = sfv[(ib + 16 + n) * 8 + 4 + q];

  union { unsigned u; h2 v; } infu; infu.u = 0x7C007C00u;  // (+inf, +inf)
  h2 lst[16];
#pragma unroll
  for (int k = 0; k < 16; ++k) lst[k] = infu.v;

  const int j0 = js * 1024 + wave * 256;
  short8 A0 = sfv[(j0 + n) * 8 + q];
  short8 A1 = sfv[(j0 + n) * 8 + 4 + q];
  floatx4 s4 = *(const floatx4*)(sq + j0 + q * 4);

  for (int jt = 0; jt < 256; jt += 16) {
    const int jn = j0 + jt + 16;   // final prefetch overruns into ws scratch: harmless
    short8 nA0 = sfv[(jn + n) * 8 + q];
    short8 nA1 = sfv[(jn + n) * 8 + 4 + q];
    floatx4 ns4 = *(const floatx4*)(sq + jn + q * 4);
    __builtin_amdgcn_sched_barrier(0);

    floatx4 acc0 = {0, 0, 0, 0};
    acc0 = __builtin_amdgcn_mfma_f32_16x16x32_bf16(A0, b0, acc0, 0, 0, 0);
    acc0 = __builtin_amdgcn_mfma_f32_16x16x32_bf16(A1, b1, acc0, 0, 0, 0);
    floatx4 acc1 = {0, 0, 0, 0};
    acc1 = __builtin_amdgcn_mfma_f32_16x16x32_bf16(A0, b2, acc1, 0, 0, 0);
    acc1 = __builtin_amdgcn_mfma_f32_16x16x32_bf16(A1, b3, acc1, 0, 0, 0);

#pragma unroll
    for (int r = 0; r < 4; ++r) {
      float c0 = fmaf(-2.0f, acc0[r], s4[r]);   // key = sq_j - 2*dot
      float c1 = fmaf(-2.0f, acc1[r], s4[r]);
      h2 c2 = __builtin_amdgcn_cvt_pkrtz(c0, c1);
#pragma unroll
      for (int k = 15; k >= 1; --k)
        lst[k] = __builtin_elementwise_min(lst[k],
                   __builtin_elementwise_max(lst[k - 1], c2));
      lst[0] = __builtin_elementwise_min(lst[0], c2);
    }
    A0 = nA0; A1 = nA1; s4 = ns4;
  }

  // lists[sl*273 + n*17 + k]: u32 packs rows (n, n+16); stride 273 = 17 mod 32
  __shared__ unsigned lists[16 * 273];
  const int sl = wave * 4 + q;
#pragma unroll
  for (int k = 0; k < 16; ++k) {
    union { h2 v; unsigned u; } t; t.v = lst[k];
    lists[sl * 273 + n * 17 + k] = t.u;
  }
  __syncthreads();

  // Tournament: 16 sublists/row, sortable-u16 keys | 4-bit sublist id.
  const int sub = lane & 15;
#pragma unroll 1
  for (int pass = 0; pass < 2; ++pass) {
    const int rr = pass * 16 + wave * 4 + (lane >> 4);   // 0..31
    const int nr = rr & 15, sh = (rr >> 4) * 16;
    int p = 0;
    unsigned hb = (lists[sub * 273 + nr * 17] >> sh) & 0xFFFFu;
    unsigned key = ((hb ^ ((hb & 0x8000u) ? 0xFFFFu : 0x8000u)) << 4) | (unsigned)sub;
    float* trow = tops + ((size_t)(ib + rr) * 8 + js) * 16;
#pragma unroll 1
    for (int it = 0; it < 16; ++it) {
      unsigned u = key;
#pragma unroll
      for (int off = 1; off < 16; off <<= 1) {
        unsigned u2 = __shfl_xor(u, off, 64);
        u = (u2 < u) ? u2 : u;
      }
      if (sub == 0) {
        unsigned s16 = (u >> 4) & 0xFFFFu;
        union { unsigned short b; __fp16 f; } cv;
        cv.b = (unsigned short)(s16 ^ ((s16 & 0x8000u) ? 0x8000u : 0xFFFFu));
        trow[it] = (float)cv.f;
      }
      if ((u & 15u) == (unsigned)sub) {
        ++p;
        hb = (lists[sub * 273 + nr * 17 + p] >> sh) & 0xFFFFu;
        key = ((hb ^ ((hb & 0x8000u) ? 0xFFFFu : 0x8000u)) << 4) | (unsigned)sub;
      }
    }
  }

  // Last-block merge (rocPRIM pattern): 8th js-block for this row-group.
  __syncthreads();
  __shared__ int lastFlag;
  __shared__ float rsum[32];
  if (tid == 0) {
    __threadfence();                       // release trow writes
    unsigned old = atomicAdd(&cnt[rg], 1u);
    lastFlag = (old == 7u) ? 1 : 0;
  }
  __syncthreads();
  if (!lastFlag) return;
  __threadfence();                         // acquire other blocks' trow writes
  if (tid < 32) {
    const int row = ib + tid;
    float l[16];
#pragma unroll
    for (int k = 0; k < 16; ++k) l[k] = 3.0e38f;
    const float* tr = tops + (size_t)row * 128;
#pragma unroll 1
    for (int s8 = 0; s8 < 8; ++s8) {
      const float* seg = tr + s8 * 16;
#pragma unroll 1
      for (int it = 0; it < 16; ++it) {
        float c = seg[it];
        if (c >= l[15]) break;             // seg sorted ascending -> done
#pragma unroll
        for (int k = 15; k >= 1; --k)
          l[k] = __builtin_amdgcn_fmed3f(l[k], l[k - 1], c);
        l[0] = fminf(l[0], c);
      }
    }
    const float sqr = sq[row];
    float sum = 0.0f;
#pragma unroll
    for (int k = 0; k < 16; ++k) sum += sqrtf(fmaxf(sqr + l[k], 1e-12f));
    float ir = sum * (1.0f / 16.0f);
    intrew[row] = ir;
    rsum[tid] = ir;
  }
  __syncthreads();
  if (tid == 0) {
    float s = 0.0f;
#pragma unroll
    for (int k = 0; k < 32; ++k) s += rsum[k];
    atomicAdd(psum, s);
  }
}

// K3: StreamNorm + add reward
__global__ __launch_bounds__(256) void k_final(const float* __restrict__ reward,
                                               const float* __restrict__ intrew,
                                               const float* __restrict__ psum,
                                               float* __restrict__ out) {
  int i = blockIdx.x * 256 + threadIdx.x;   // 0..8191
  float mean = psum[0] * (1.0f / 8192.0f);
  float mag = 0.99f + 0.01f * mean;
  int b = i >> 9, ti = i & 511;
  out[i] = reward[b * TT + ti] + intrew[i] / (mag + 1e-8f);
}

extern "C" void kernel_launch(void* const* d_in, const int* in_sizes, int n_in,
                              void* d_out, int out_size, void* d_ws, size_t ws_size,
                              hipStream_t stream) {
  const float* feat   = (const float*)d_in[0];
  const float* reward = (const float*)d_in[1];
  const float* proj   = (const float*)d_in[2];
  float* out = (float*)d_out;

  char* ws = (char*)d_ws;
  unsigned short* sfb = (unsigned short*)ws;                   // 1 MB: sf bf16 [8192][64]
  float* sq           = (float*)(ws + 0x100000);               // 32 KB
  float* intrew       = (float*)(ws + 0x110000);               // 32 KB
  float* psum         = (float*)(ws + 0x120000);               // 4 B
  unsigned* cnt       = (unsigned*)(ws + 0x120100);            // 1 KB: per row-group
  float* tops         = (float*)(ws + 0x160000);               // 4 MB: [8192][8][16]

  k_sf<<<512, 256, 0, stream>>>(feat, proj, sfb, sq, cnt, psum);
  k_knn<<<2048, 256, 0, stream>>>(sfb, sq, tops, intrew, cnt, psum);
  k_final<<<32, 256, 0, stream>>>(reward, intrew, psum, out);
}

// Round 8
// 264.618 us; speedup vs baseline: 1.5798x; 1.5798x over previous
//
#include <hip/hip_runtime.h>
#include <hip/hip_bf16.h>
#include <stdint.h>

typedef __attribute__((ext_vector_type(8))) short short8;
typedef __attribute__((ext_vector_type(4))) float floatx4;

#define FEAT_DIM 1536
#define QD 64
#define NROWS 8192
#define TT 513

__device__ __forceinline__ unsigned short f2bf(float x) {
  union { float f; unsigned u; } t; t.f = x;
  unsigned r = t.u + 0x7fffu + ((t.u >> 16) & 1u);
  return (unsigned short)(r >> 16);
}
__device__ __forceinline__ float bf2f(unsigned short u) {
  union { float f; unsigned u; } t; t.u = ((unsigned)u) << 16;
  return t.f;
}
// monotone float->uint map (order-preserving), low 4 bits freed for an index
__device__ __forceinline__ unsigned packkey(float f, int idx) {
  unsigned x = __float_as_uint(f);
  unsigned m = (unsigned)((int)x >> 31);
  unsigned u = x ^ (m | 0x80000000u);
  return (u & ~15u) | (unsigned)idx;
}
__device__ __forceinline__ float unpackkey(unsigned u) {
  u &= ~15u;
  unsigned x = (u & 0x80000000u) ? (u ^ 0x80000000u) : ~u;
  return __uint_as_float(x);
}

// K1: sf = win @ proj (MFMA bf16), proj transposed+converted on the fly.
// Also zero-inits cnt[256] + psum (runs before k_knn in stream order).
__global__ __launch_bounds__(256, 4) void k_sf(const float* __restrict__ feat,
                                               const float* __restrict__ proj,
                                               unsigned short* __restrict__ sfb,
                                               float* __restrict__ sq,
                                               unsigned* __restrict__ cnt,
                                               float* __restrict__ psum) {
  if (threadIdx.x == 0) {
    if (blockIdx.x < 256) cnt[blockIdx.x] = 0u;
    if (blockIdx.x == 256) *psum = 0.0f;
  }
  const int tid = threadIdx.x;
  const int wave = tid >> 6, lane = tid & 63;
  const int q = lane >> 4, n = lane & 15;
  const int rbase = blockIdx.x * 16;
  const int row = rbase + n;
  const int b = row >> 9, ti = row & 511;
  const float* fb = feat + (size_t)(b * TT + ti) * FEAT_DIM;
  const int kw = wave * 384;

  floatx4 acc0 = {0,0,0,0}, acc1 = {0,0,0,0}, acc2 = {0,0,0,0}, acc3 = {0,0,0,0};

  int koff = kw + q * 8;
  floatx4 f0 = *(const floatx4*)(fb + koff);
  floatx4 f1 = *(const floatx4*)(fb + koff + 4);
  floatx4 g0 = *(const floatx4*)(fb + FEAT_DIM + koff);
  floatx4 g1 = *(const floatx4*)(fb + FEAT_DIM + koff + 4);

  for (int ks = 0; ks < 12; ++ks) {
    floatx4 nf0, nf1, ng0, ng1;
    if (ks < 11) {
      int ko = kw + (ks + 1) * 32 + q * 8;
      nf0 = *(const floatx4*)(fb + ko);
      nf1 = *(const floatx4*)(fb + ko + 4);
      ng0 = *(const floatx4*)(fb + FEAT_DIM + ko);
      ng1 = *(const floatx4*)(fb + FEAT_DIM + ko + 4);
    }
    const float* pp = proj + (size_t)(kw + ks * 32 + q * 8) * QD + n;
    union { unsigned short u[8]; short8 v; } B0, B1, B2, B3;
#pragma unroll
    for (int j = 0; j < 8; ++j) {
      B0.u[j] = f2bf(pp[j * QD]);
      B1.u[j] = f2bf(pp[j * QD + 16]);
      B2.u[j] = f2bf(pp[j * QD + 32]);
      B3.u[j] = f2bf(pp[j * QD + 48]);
    }
    __builtin_amdgcn_sched_barrier(0);
    union { unsigned short u[8]; short8 v; } A;
#pragma unroll
    for (int j = 0; j < 4; ++j) A.u[j] = f2bf(0.5f * (f0[j] + g0[j]));
#pragma unroll
    for (int j = 0; j < 4; ++j) A.u[4 + j] = f2bf(0.5f * (f1[j] + g1[j]));
    acc0 = __builtin_amdgcn_mfma_f32_16x16x32_bf16(A.v, B0.v, acc0, 0, 0, 0);
    acc1 = __builtin_amdgcn_mfma_f32_16x16x32_bf16(A.v, B1.v, acc1, 0, 0, 0);
    acc2 = __builtin_amdgcn_mfma_f32_16x16x32_bf16(A.v, B2.v, acc2, 0, 0, 0);
    acc3 = __builtin_amdgcn_mfma_f32_16x16x32_bf16(A.v, B3.v, acc3, 0, 0, 0);
    if (ks < 11) { f0 = nf0; f1 = nf1; g0 = ng0; g1 = ng1; }
  }

  __shared__ float part[4][16][64];
#pragma unroll
  for (int r = 0; r < 4; ++r) {
    part[wave][q * 4 + r][0 * 16 + n] = acc0[r];
    part[wave][q * 4 + r][1 * 16 + n] = acc1[r];
    part[wave][q * 4 + r][2 * 16 + n] = acc2[r];
    part[wave][q * 4 + r][3 * 16 + n] = acc3[r];
  }
  __syncthreads();
  {
    const int r = tid >> 4;
    const int c0 = (tid & 15) * 4;
    float sqp = 0.0f;
    union { unsigned short u[4]; uint2 d; } P;
#pragma unroll
    for (int j = 0; j < 4; ++j) {
      float v = part[0][r][c0 + j] + part[1][r][c0 + j] +
                part[2][r][c0 + j] + part[3][r][c0 + j];
      P.u[j] = f2bf(v);
      float bv = bf2f(P.u[j]);
      sqp += bv * bv;
    }
    *(uint2*)(sfb + (size_t)(rbase + r) * QD + c0) = P.d;
#pragma unroll
    for (int off = 1; off < 16; off <<= 1) sqp += __shfl_xor(sqp, off, 64);
    if ((tid & 15) == 0) sq[rbase + r] = sqp;
  }
}

// K2: pairwise-dot (MFMA) + per-row top-16 via fp32 med3 insert nets (R5 loop —
// measured 59.8 us). Block = (32-row i-tile) x (js of 2048 j's); wave covers
// 512 j's; lane owns TWO i-lists. Last-of-4 js-block merges -> intrew + psum.
__global__ __launch_bounds__(256, 4) void k_knn(const unsigned short* __restrict__ sfb,
                                                const float* __restrict__ sq,
                                                float* __restrict__ tops,
                                                float* __restrict__ intrew,
                                                unsigned* __restrict__ cnt,
                                                float* __restrict__ psum) {
  const int tid = threadIdx.x;
  const int wave = tid >> 6, lane = tid & 63;
  const int q = lane >> 4, n = lane & 15;
  const int rg = blockIdx.x >> 2;          // row-group 0..255
  const int ib = rg * 32;
  const int js = blockIdx.x & 3;
  const short8* sfv = (const short8*)sfb;

  short8 b0 = sfv[(ib + n) * 8 + q];
  short8 b1 = sfv[(ib + n) * 8 + 4 + q];
  short8 b2 = sfv[(ib + 16 + n) * 8 + q];
  short8 b3 = sfv[(ib + 16 + n) * 8 + 4 + q];

  float lst0[16], lst1[16];
#pragma unroll
  for (int k = 0; k < 16; ++k) { lst0[k] = 3.0e38f; lst1[k] = 3.0e38f; }

  const int j0 = js * 2048 + wave * 512;
  short8 A0 = sfv[(j0 + n) * 8 + q];
  short8 A1 = sfv[(j0 + n) * 8 + 4 + q];
  floatx4 s4 = *(const floatx4*)(sq + j0 + q * 4);

  for (int jt = 0; jt < 512; jt += 16) {
    const int jn = j0 + jt + 16;   // final prefetch overruns into ws scratch: harmless
    short8 nA0 = sfv[(jn + n) * 8 + q];
    short8 nA1 = sfv[(jn + n) * 8 + 4 + q];
    floatx4 ns4 = *(const floatx4*)(sq + jn + q * 4);
    __builtin_amdgcn_sched_barrier(0);

    floatx4 acc0 = {0, 0, 0, 0};
    acc0 = __builtin_amdgcn_mfma_f32_16x16x32_bf16(A0, b0, acc0, 0, 0, 0);
    acc0 = __builtin_amdgcn_mfma_f32_16x16x32_bf16(A1, b1, acc0, 0, 0, 0);
    floatx4 acc1 = {0, 0, 0, 0};
    acc1 = __builtin_amdgcn_mfma_f32_16x16x32_bf16(A0, b2, acc1, 0, 0, 0);
    acc1 = __builtin_amdgcn_mfma_f32_16x16x32_bf16(A1, b3, acc1, 0, 0, 0);

#pragma unroll
    for (int r = 0; r < 4; ++r) {
      float c = fmaf(-2.0f, acc0[r], s4[r]);   // key = sq_j - 2*dot
#pragma unroll
      for (int k = 15; k >= 1; --k)
        lst0[k] = __builtin_amdgcn_fmed3f(lst0[k], lst0[k - 1], c);
      lst0[0] = fminf(lst0[0], c);
    }
#pragma unroll
    for (int r = 0; r < 4; ++r) {
      float c = fmaf(-2.0f, acc1[r], s4[r]);
#pragma unroll
      for (int k = 15; k >= 1; --k)
        lst1[k] = __builtin_amdgcn_fmed3f(lst1[k], lst1[k - 1], c);
      lst1[0] = fminf(lst1[0], c);
    }
    A0 = nA0; A1 = nA1; s4 = ns4;
  }

  // flat LDS, sublist stride 547 (== 3 mod 32, invertible): head reloads across
  // the 16 sublists hit 16 distinct banks (R5's stride 544 was 16-way conflicted)
  __shared__ unsigned lists[16 * 547];
  const int sl = wave * 4 + q;
#pragma unroll
  for (int k = 0; k < 16; ++k) {
    lists[sl * 547 + n * 17 + k] = packkey(lst0[k], sl);
    lists[sl * 547 + (n + 16) * 17 + k] = packkey(lst1[k], sl);
  }
  __syncthreads();

  // Tournament: 16 sublists/row, sortable-u32 keys | 4-bit sublist id.
  const int sub = lane & 15;
#pragma unroll 1
  for (int pass = 0; pass < 2; ++pass) {
    const int rr = pass * 16 + wave * 4 + (lane >> 4);   // 0..31
    int p = 0;
    unsigned h = lists[sub * 547 + rr * 17];
    float* trow = tops + ((size_t)(ib + rr) * 4 + js) * 16;
#pragma unroll 1
    for (int it = 0; it < 16; ++it) {
      unsigned u = h;
#pragma unroll
      for (int off = 1; off < 16; off <<= 1) {
        unsigned u2 = __shfl_xor(u, off, 64);
        u = (u2 < u) ? u2 : u;
      }
      if (sub == 0) trow[it] = unpackkey(u);
      if ((u & 15u) == (unsigned)sub) { ++p; h = lists[sub * 547 + rr * 17 + p]; }
    }
  }

  // Last-block merge (rocPRIM pattern): 4th js-block for this row-group.
  __syncthreads();
  __shared__ int lastFlag;
  __shared__ float rsum[32];
  if (tid == 0) {
    __threadfence();                       // release trow writes
    unsigned old = atomicAdd(&cnt[rg], 1u);
    lastFlag = (old == 3u) ? 1 : 0;
  }
  __syncthreads();
  if (!lastFlag) return;
  __threadfence();                         // acquire other blocks' trow writes
  if (tid < 32) {
    const int row = ib + tid;
    float l[16];
#pragma unroll
    for (int k = 0; k < 16; ++k) l[k] = 3.0e38f;
    const float* tr = tops + (size_t)row * 64;
#pragma unroll 1
    for (int s4i = 0; s4i < 4; ++s4i) {
      const float* seg = tr + s4i * 16;
#pragma unroll 1
      for (int it = 0; it < 16; ++it) {
        float c = seg[it];
        if (c >= l[15]) break;             // seg sorted ascending -> done
#pragma unroll
        for (int k = 15; k >= 1; --k)
          l[k] = __builtin_amdgcn_fmed3f(l[k], l[k - 1], c);
        l[0] = fminf(l[0], c);
      }
    }
    const float sqr = sq[row];
    float sum = 0.0f;
#pragma unroll
    for (int k = 0; k < 16; ++k) sum += sqrtf(fmaxf(sqr + l[k], 1e-12f));
    float ir = sum * (1.0f / 16.0f);
    intrew[row] = ir;
    rsum[tid] = ir;
  }
  __syncthreads();
  if (tid == 0) {
    float s = 0.0f;
#pragma unroll
    for (int k = 0; k < 32; ++k) s += rsum[k];
    atomicAdd(psum, s);
  }
}

// K3: StreamNorm + add reward
__global__ __launch_bounds__(256) void k_final(const float* __restrict__ reward,
                                               const float* __restrict__ intrew,
                                               const float* __restrict__ psum,
                                               float* __restrict__ out) {
  int i = blockIdx.x * 256 + threadIdx.x;   // 0..8191
  float mean = psum[0] * (1.0f / 8192.0f);
  float mag = 0.99f + 0.01f * mean;
  int b = i >> 9, ti = i & 511;
  out[i] = reward[b * TT + ti] + intrew[i] / (mag + 1e-8f);
}

extern "C" void kernel_launch(void* const* d_in, const int* in_sizes, int n_in,
                              void* d_out, int out_size, void* d_ws, size_t ws_size,
                              hipStream_t stream) {
  const float* feat   = (const float*)d_in[0];
  const float* reward = (const float*)d_in[1];
  const float* proj   = (const float*)d_in[2];
  float* out = (float*)d_out;

  char* ws = (char*)d_ws;
  unsigned short* sfb = (unsigned short*)ws;                   // 1 MB: sf bf16 [8192][64]
  float* sq           = (float*)(ws + 0x100000);               // 32 KB
  float* intrew       = (float*)(ws + 0x110000);               // 32 KB
  float* psum         = (float*)(ws + 0x120000);               // 4 B
  unsigned* cnt       = (unsigned*)(ws + 0x120100);            // 1 KB: per row-group
  float* tops         = (float*)(ws + 0x160000);               // 2 MB: [8192][4][16]

  k_sf<<<512, 256, 0, stream>>>(feat, proj, sfb, sq, cnt, psum);
  k_knn<<<1024, 256, 0, stream>>>(sfb, sq, tops, intrew, cnt, psum);
  k_final<<<32, 256, 0, stream>>>(reward, intrew, psum, out);
}

// Round 9
// 165.453 us; speedup vs baseline: 2.5266x; 1.5994x over previous
//
#include <hip/hip_runtime.h>
#include <hip/hip_bf16.h>
#include <stdint.h>

typedef __attribute__((ext_vector_type(8))) short short8;
typedef __attribute__((ext_vector_type(4))) float floatx4;

#define FEAT_DIM 1536
#define QD 64
#define NROWS 8192
#define TT 513

__device__ __forceinline__ unsigned short f2bf(float x) {
  union { float f; unsigned u; } t; t.f = x;
  unsigned r = t.u + 0x7fffu + ((t.u >> 16) & 1u);
  return (unsigned short)(r >> 16);
}
__device__ __forceinline__ float bf2f(unsigned short u) {
  union { float f; unsigned u; } t; t.u = ((unsigned)u) << 16;
  return t.f;
}
// monotone float->uint map (order-preserving), low 4 bits freed for an index
__device__ __forceinline__ unsigned packkey(float f, int idx) {
  unsigned x = __float_as_uint(f);
  unsigned m = (unsigned)((int)x >> 31);
  unsigned u = x ^ (m | 0x80000000u);
  return (u & ~15u) | (unsigned)idx;
}
__device__ __forceinline__ float unpackkey(unsigned u) {
  u &= ~15u;
  unsigned x = (u & 0x80000000u) ? (u ^ 0x80000000u) : ~u;
  return __uint_as_float(x);
}

// K1: sf = win @ proj (MFMA bf16), proj transposed+converted on the fly.
// (Unchanged from R5 so its duration finally shows in the profile.)
__global__ __launch_bounds__(256, 4) void k_sf(const float* __restrict__ feat,
                                               const float* __restrict__ proj,
                                               unsigned short* __restrict__ sfb,
                                               float* __restrict__ sq) {
  const int tid = threadIdx.x;
  const int wave = tid >> 6, lane = tid & 63;
  const int q = lane >> 4, n = lane & 15;
  const int rbase = blockIdx.x * 16;
  const int row = rbase + n;
  const int b = row >> 9, ti = row & 511;
  const float* fb = feat + (size_t)(b * TT + ti) * FEAT_DIM;
  const int kw = wave * 384;

  floatx4 acc0 = {0,0,0,0}, acc1 = {0,0,0,0}, acc2 = {0,0,0,0}, acc3 = {0,0,0,0};

  int koff = kw + q * 8;
  floatx4 f0 = *(const floatx4*)(fb + koff);
  floatx4 f1 = *(const floatx4*)(fb + koff + 4);
  floatx4 g0 = *(const floatx4*)(fb + FEAT_DIM + koff);
  floatx4 g1 = *(const floatx4*)(fb + FEAT_DIM + koff + 4);

  for (int ks = 0; ks < 12; ++ks) {
    floatx4 nf0, nf1, ng0, ng1;
    if (ks < 11) {
      int ko = kw + (ks + 1) * 32 + q * 8;
      nf0 = *(const floatx4*)(fb + ko);
      nf1 = *(const floatx4*)(fb + ko + 4);
      ng0 = *(const floatx4*)(fb + FEAT_DIM + ko);
      ng1 = *(const floatx4*)(fb + FEAT_DIM + ko + 4);
    }
    const float* pp = proj + (size_t)(kw + ks * 32 + q * 8) * QD + n;
    union { unsigned short u[8]; short8 v; } B0, B1, B2, B3;
#pragma unroll
    for (int j = 0; j < 8; ++j) {
      B0.u[j] = f2bf(pp[j * QD]);
      B1.u[j] = f2bf(pp[j * QD + 16]);
      B2.u[j] = f2bf(pp[j * QD + 32]);
      B3.u[j] = f2bf(pp[j * QD + 48]);
    }
    __builtin_amdgcn_sched_barrier(0);
    union { unsigned short u[8]; short8 v; } A;
#pragma unroll
    for (int j = 0; j < 4; ++j) A.u[j] = f2bf(0.5f * (f0[j] + g0[j]));
#pragma unroll
    for (int j = 0; j < 4; ++j) A.u[4 + j] = f2bf(0.5f * (f1[j] + g1[j]));
    acc0 = __builtin_amdgcn_mfma_f32_16x16x32_bf16(A.v, B0.v, acc0, 0, 0, 0);
    acc1 = __builtin_amdgcn_mfma_f32_16x16x32_bf16(A.v, B1.v, acc1, 0, 0, 0);
    acc2 = __builtin_amdgcn_mfma_f32_16x16x32_bf16(A.v, B2.v, acc2, 0, 0, 0);
    acc3 = __builtin_amdgcn_mfma_f32_16x16x32_bf16(A.v, B3.v, acc3, 0, 0, 0);
    if (ks < 11) { f0 = nf0; f1 = nf1; g0 = ng0; g1 = ng1; }
  }

  __shared__ float part[4][16][64];
#pragma unroll
  for (int r = 0; r < 4; ++r) {
    part[wave][q * 4 + r][0 * 16 + n] = acc0[r];
    part[wave][q * 4 + r][1 * 16 + n] = acc1[r];
    part[wave][q * 4 + r][2 * 16 + n] = acc2[r];
    part[wave][q * 4 + r][3 * 16 + n] = acc3[r];
  }
  __syncthreads();
  {
    const int r = tid >> 4;
    const int c0 = (tid & 15) * 4;
    float sqp = 0.0f;
    union { unsigned short u[4]; uint2 d; } P;
#pragma unroll
    for (int j = 0; j < 4; ++j) {
      float v = part[0][r][c0 + j] + part[1][r][c0 + j] +
                part[2][r][c0 + j] + part[3][r][c0 + j];
      P.u[j] = f2bf(v);
      float bv = bf2f(P.u[j]);
      sqp += bv * bv;
    }
    *(uint2*)(sfb + (size_t)(rbase + r) * QD + c0) = P.d;
#pragma unroll
    for (int off = 1; off < 16; off <<= 1) sqp += __shfl_xor(sqp, off, 64);
    if ((tid & 15) == 0) sq[rbase + r] = sqp;
  }
}

// K2: pairwise-dot (MFMA) + per-row top-16 via fp32 med3 insert nets.
// R5's measured-59.8us loop; stride-547 tournament LDS (conflict fix);
// NO fused tail, NO fences (R8 lesson: agent-scope fences nuke L2 for
// in-flight blocks; 59.8 -> 190us). Pure producer: sfb,sq -> tops.
__global__ __launch_bounds__(256, 4) void k_knn(const unsigned short* __restrict__ sfb,
                                                const float* __restrict__ sq,
                                                float* __restrict__ tops) {
  const int tid = threadIdx.x;
  const int wave = tid >> 6, lane = tid & 63;
  const int q = lane >> 4, n = lane & 15;
  const int ib = (blockIdx.x >> 2) * 32;
  const int js = blockIdx.x & 3;
  const short8* sfv = (const short8*)sfb;

  short8 b0 = sfv[(ib + n) * 8 + q];
  short8 b1 = sfv[(ib + n) * 8 + 4 + q];
  short8 b2 = sfv[(ib + 16 + n) * 8 + q];
  short8 b3 = sfv[(ib + 16 + n) * 8 + 4 + q];

  float lst0[16], lst1[16];
#pragma unroll
  for (int k = 0; k < 16; ++k) { lst0[k] = 3.0e38f; lst1[k] = 3.0e38f; }

  const int j0 = js * 2048 + wave * 512;
  short8 A0 = sfv[(j0 + n) * 8 + q];
  short8 A1 = sfv[(j0 + n) * 8 + 4 + q];
  floatx4 s4 = *(const floatx4*)(sq + j0 + q * 4);

  for (int jt = 0; jt < 512; jt += 16) {
    const int jn = j0 + jt + 16;   // final prefetch overruns into ws scratch: harmless
    short8 nA0 = sfv[(jn + n) * 8 + q];
    short8 nA1 = sfv[(jn + n) * 8 + 4 + q];
    floatx4 ns4 = *(const floatx4*)(sq + jn + q * 4);
    __builtin_amdgcn_sched_barrier(0);

    floatx4 acc0 = {0, 0, 0, 0};
    acc0 = __builtin_amdgcn_mfma_f32_16x16x32_bf16(A0, b0, acc0, 0, 0, 0);
    acc0 = __builtin_amdgcn_mfma_f32_16x16x32_bf16(A1, b1, acc0, 0, 0, 0);
    floatx4 acc1 = {0, 0, 0, 0};
    acc1 = __builtin_amdgcn_mfma_f32_16x16x32_bf16(A0, b2, acc1, 0, 0, 0);
    acc1 = __builtin_amdgcn_mfma_f32_16x16x32_bf16(A1, b3, acc1, 0, 0, 0);

#pragma unroll
    for (int r = 0; r < 4; ++r) {
      float c = fmaf(-2.0f, acc0[r], s4[r]);   // key = sq_j - 2*dot
#pragma unroll
      for (int k = 15; k >= 1; --k)
        lst0[k] = __builtin_amdgcn_fmed3f(lst0[k], lst0[k - 1], c);
      lst0[0] = fminf(lst0[0], c);
    }
#pragma unroll
    for (int r = 0; r < 4; ++r) {
      float c = fmaf(-2.0f, acc1[r], s4[r]);
#pragma unroll
      for (int k = 15; k >= 1; --k)
        lst1[k] = __builtin_amdgcn_fmed3f(lst1[k], lst1[k - 1], c);
      lst1[0] = fminf(lst1[0], c);
    }
    A0 = nA0; A1 = nA1; s4 = ns4;
  }

  // flat LDS, sublist stride 547 (== 3 mod 32): tournament head reloads across
  // the 16 sublists hit distinct banks (R5's [16][32][17] stride 544 was 16-way)
  __shared__ unsigned lists[16 * 547];
  const int sl = wave * 4 + q;
#pragma unroll
  for (int k = 0; k < 16; ++k) {
    lists[sl * 547 + n * 17 + k] = packkey(lst0[k], sl);
    lists[sl * 547 + (n + 16) * 17 + k] = packkey(lst1[k], sl);
  }
  __syncthreads();

  // Tournament: 16 sublists/row, sortable-u32 keys | 4-bit sublist id.
  const int sub = lane & 15;
#pragma unroll 1
  for (int pass = 0; pass < 2; ++pass) {
    const int rr = pass * 16 + wave * 4 + (lane >> 4);   // 0..31
    int p = 0;
    unsigned h = lists[sub * 547 + rr * 17];
    float* trow = tops + ((size_t)(ib + rr) * 4 + js) * 16;
#pragma unroll 1
    for (int it = 0; it < 16; ++it) {
      unsigned u = h;
#pragma unroll
      for (int off = 1; off < 16; off <<= 1) {
        unsigned u2 = __shfl_xor(u, off, 64);
        u = (u2 < u) ? u2 : u;
      }
      if (sub == 0) trow[it] = unpackkey(u);
      if ((u & 15u) == (unsigned)sub) { ++p; h = lists[sub * 547 + rr * 17 + p]; }
    }
  }
}

// K2b: thread-per-row 4-way MERGE of 4 sorted 16-segments (16 steps, 3 fmin +
// 1 LDS refill per step) -> sqrt-sum. Replaces R5's 1024-serial-med3 insert
// version (~45us for a 32-block kernel). psum[block] array: no atomics.
__global__ __launch_bounds__(256) void k_merge(const float* __restrict__ tops,
                                               const float* __restrict__ sq,
                                               float* __restrict__ intrew,
                                               float* __restrict__ psum) {
  const int tid = threadIdx.x;
  __shared__ float buf[256][65];
  const size_t base = (size_t)blockIdx.x * 256 * 64;
#pragma unroll 1
  for (int j = 0; j < 64; ++j) {
    int f = j * 256 + tid;
    buf[f >> 6][f & 63] = tops[base + f];
  }
  __syncthreads();

  const int row = blockIdx.x * 256 + tid;
  const float sqr = sq[row];
  int c0 = 1, c1 = 17, c2 = 33, c3 = 49;
  float h0 = buf[tid][0], h1 = buf[tid][16], h2 = buf[tid][32], h3 = buf[tid][48];
  float sum = 0.0f;
#pragma unroll 1
  for (int it = 0; it < 16; ++it) {
    float m = fminf(fminf(h0, h1), fminf(h2, h3));
    sum += sqrtf(fmaxf(sqr + m, 1e-12f));
    if (m == h0)      { h0 = (c0 < 16) ? buf[tid][c0] : 3.0e38f; ++c0; }
    else if (m == h1) { h1 = (c1 < 32) ? buf[tid][c1] : 3.0e38f; ++c1; }
    else if (m == h2) { h2 = (c2 < 48) ? buf[tid][c2] : 3.0e38f; ++c2; }
    else              { h3 = (c3 < 64) ? buf[tid][c3] : 3.0e38f; ++c3; }
  }
  float ir = sum * (1.0f / 16.0f);
  intrew[row] = ir;

  float w = ir;
#pragma unroll
  for (int off = 1; off < 64; off <<= 1) w += __shfl_xor(w, off, 64);
  __shared__ float ws4[4];
  if ((tid & 63) == 0) ws4[tid >> 6] = w;
  __syncthreads();
  if (tid == 0) psum[blockIdx.x] = ws4[0] + ws4[1] + ws4[2] + ws4[3];
}

// K3: StreamNorm + add reward (psum has 32 block sums)
__global__ __launch_bounds__(256) void k_final(const float* __restrict__ reward,
                                               const float* __restrict__ intrew,
                                               const float* __restrict__ psum,
                                               float* __restrict__ out) {
  int i = blockIdx.x * 256 + threadIdx.x;   // 0..8191
  float total = 0.0f;
#pragma unroll
  for (int k = 0; k < 32; ++k) total += psum[k];
  float mean = total * (1.0f / 8192.0f);
  float mag = 0.99f + 0.01f * mean;
  int b = i >> 9, ti = i & 511;
  out[i] = reward[b * TT + ti] + intrew[i] / (mag + 1e-8f);
}

extern "C" void kernel_launch(void* const* d_in, const int* in_sizes, int n_in,
                              void* d_out, int out_size, void* d_ws, size_t ws_size,
                              hipStream_t stream) {
  const float* feat   = (const float*)d_in[0];
  const float* reward = (const float*)d_in[1];
  const float* proj   = (const float*)d_in[2];
  float* out = (float*)d_out;

  char* ws = (char*)d_ws;
  unsigned short* sfb = (unsigned short*)ws;                   // 1 MB: sf bf16 [8192][64]
  float* sq           = (float*)(ws + 0x100000);               // 32 KB
  float* intrew       = (float*)(ws + 0x110000);               // 32 KB
  float* psum         = (float*)(ws + 0x120000);               // 128 B
  float* tops         = (float*)(ws + 0x160000);               // 2 MB: [8192][4][16]

  k_sf<<<512, 256, 0, stream>>>(feat, proj, sfb, sq);
  k_knn<<<1024, 256, 0, stream>>>(sfb, sq, tops);
  k_merge<<<32, 256, 0, stream>>>(tops, sq, intrew, psum);
  k_final<<<32, 256, 0, stream>>>(reward, intrew, psum, out);
}